// Round 3
// baseline (356.998 us; speedup 1.0000x reference)
//
#include <hip/hip_runtime.h>
#include <hip/hip_bf16.h>

// ---------- types ----------
typedef __bf16 bf16x8 __attribute__((ext_vector_type(8)));
typedef float  f32x4  __attribute__((ext_vector_type(4)));

#define GLOAD_LDS16(gptr, lptr)                                                  \
  __builtin_amdgcn_global_load_lds(                                              \
      (const __attribute__((address_space(1))) void*)(gptr),                     \
      (__attribute__((address_space(3))) void*)(lptr), 16, 0, 0)

__device__ __forceinline__ unsigned short f2bf(float f) {
  __hip_bfloat16 h = __float2bfloat16(f);
  return __builtin_bit_cast(unsigned short, h);
}

// ---------- fake-quant: lane owns 4 CONSECUTIVE floats; the 128-elem block is
// the 32-lane half-wave. amax via 5-step butterfly (exact - fmax associative).
__device__ __forceinline__ void fq4(float* __restrict__ v) {
  float am = fmaxf(fmaxf(fabsf(v[0]), fabsf(v[1])),
                   fmaxf(fabsf(v[2]), fabsf(v[3])));
  am = fmaxf(am, __shfl_xor(am, 1));
  am = fmaxf(am, __shfl_xor(am, 2));
  am = fmaxf(am, __shfl_xor(am, 4));
  am = fmaxf(am, __shfl_xor(am, 8));
  am = fmaxf(am, __shfl_xor(am, 16));   // stays within each 32-lane half
  am = fmaxf(am, 1e-12f);
  const float scale = 448.0f / am;
  const float inv   = am * (1.0f / 448.0f);
  float c0 = fminf(fmaxf(v[0] * scale, -448.0f), 448.0f);
  float c1 = fminf(fmaxf(v[1] * scale, -448.0f), 448.0f);
  float c2 = fminf(fmaxf(v[2] * scale, -448.0f), 448.0f);
  float c3 = fminf(fmaxf(v[3] * scale, -448.0f), 448.0f);
  int pk = __builtin_amdgcn_cvt_pk_fp8_f32(c0, c1, 0, false);
  pk = __builtin_amdgcn_cvt_pk_fp8_f32(c2, c3, pk, true);
  v[0] = __builtin_amdgcn_cvt_f32_fp8(pk, 0) * inv;
  v[1] = __builtin_amdgcn_cvt_f32_fp8(pk, 1) * inv;
  v[2] = __builtin_amdgcn_cvt_f32_fp8(pk, 2) * inv;
  v[3] = __builtin_amdgcn_cvt_f32_fp8(pk, 3) * inv;
}

// ---------- merged quant: blocks [0,nw) do weight dual-quant, rest do x ----
__global__ __launch_bounds__(256) void quant_xw(const float* __restrict__ x,
                                                unsigned short* __restrict__ xq,
                                                const float* __restrict__ w,
                                                unsigned short* __restrict__ wq,
                                                int nwBlocks) {
  if ((int)blockIdx.x < nwBlocks) {
    const size_t u = (size_t)blockIdx.x * 256 + threadIdx.x;
    float a[4], h[4], r[4];
    *(float4*)a = ((const float4*)w)[u];
#pragma unroll
    for (int i = 0; i < 4; ++i) h[i] = a[i];
    fq4(h);
#pragma unroll
    for (int i = 0; i < 4; ++i) r[i] = a[i] - h[i];
    fq4(r);
    union { uint2 q; unsigned short s[4]; } pk;
#pragma unroll
    for (int e = 0; e < 4; ++e) pk.s[e] = f2bf(h[e] + r[e]);
    ((uint2*)wq)[u] = pk.q;
  } else {
    const size_t u = (size_t)(blockIdx.x - nwBlocks) * 256 + threadIdx.x;
    float v[4];
    *(float4*)v = ((const float4*)x)[u];
    fq4(v);
    union { uint2 q; unsigned short s[4]; } pk;
#pragma unroll
    for (int e = 0; e < 4; ++e) pk.s[e] = f2bf(v[e]);
    ((uint2*)xq)[u] = pk.q;
  }
}

// ---------- GEMM: 256x256 tile, BK=64, 8 waves (2Mx4N) ----------------------
// A (the 64 MB cold stream) staged via global_load_lds, double-buffered 64 KB.
// B (wq, 2 MB, L2-resident) loaded DIRECTLY global->VGPR: removes 1/3 of the
// LDS read traffic (which was the binding resource: 2260 cyc/K-tile LDS vs
// 2064 cyc MFMA per CU) and all B staging. 2 phases per K-tile, 32 MFMA each.
// A gates: uniform vmcnt(10) per phase end (each phase issues 2 A-stage + 4 B
// loads; the A unit staged 2 phases earlier is 12-deep in the FIFO at its
// gate). sched_barrier(0) pins VMEM issue order so the count holds. Compiler
// auto-waits the B register loads. Requires K%128==0, K/64>=4.
#define BM 256
#define BN 256
#define BK 64

#define VMG(n) asm volatile("s_waitcnt vmcnt(" #n ")" ::: "memory")
#define LG0()  do { asm volatile("s_waitcnt lgkmcnt(0)" ::: "memory");           \
                    __builtin_amdgcn_sched_barrier(0); } while (0)
#define SB0()  __builtin_amdgcn_sched_barrier(0)
#define BAR()  __builtin_amdgcn_s_barrier()

__global__ __launch_bounds__(512, 2) void gemm_bt_bias(
    const unsigned short* __restrict__ A,   // bf16 bits [M,K]
    const unsigned short* __restrict__ B,   // bf16 bits [N,K]
    const float* __restrict__ bias,         // [N]
    float* __restrict__ C,                  // [M,N]
    int M, int N, int K) {
  __shared__ unsigned short ldsA[2 * BM * BK];   // 64 KB, A only

  const int tid  = threadIdx.x;
  const int wv   = tid >> 6;
  const int lane = tid & 63;
  const int nbn  = N / BN;
  const int nbm  = M / BM;

  int bm, bn;
  if ((nbm & 7) == 0) {
    const int xcd = blockIdx.x & 7;
    const int j   = blockIdx.x >> 3;
    bn = j % nbn;
    bm = xcd * (nbm >> 3) + j / nbn;
  } else {
    bn = blockIdx.x % nbn;
    bm = blockIdx.x / nbn;
  }

  const int wr = wv >> 2;    // 0..1 (M dir, 128 rows each)
  const int wc = wv & 3;     // 0..3 (N dir, 64 cols each)

  f32x4  acc[8][4] = {};
  bf16x8 a[4][2];
  bf16x8 b01e[2][2], b23e[2][2], b01o[2][2], b23o[2][2];

  // ---- A staging (swizzle: LDS chunk c of row r holds global chunk c^(r&7))
  const int    srcChunk = ((lane & 7) ^ ((lane >> 3) & 7)) * 8;
  const size_t laneSrc  = (size_t)(lane >> 3) * K + srcChunk;
  const unsigned short* gA = A + (size_t)bm * BM * K + laneSrc;
  const int lr0 = wv * 16, lr1 = wv * 16 + 8;
  auto arow = [](int mq, int lr) { return mq * 64 + (lr < 64 ? lr : 64 + lr); };
  const int rA[2][2] = {{arow(0, lr0), arow(0, lr1)}, {arow(1, lr0), arow(1, lr1)}};

  auto stageA = [&](int buf, int mq, int kt) {
#pragma unroll
    for (int t = 0; t < 2; ++t) {
      const int rb = rA[mq][t];
      GLOAD_LDS16(gA + (size_t)rb * K + kt * BK,
                  ldsA + buf * 16384 + rb * 64 + lane * 8);
    }
  };

  // ---- fragment addressing ----
  const int fRow = lane & 15;
  const int q4   = lane >> 4;
  const int s8   = fRow & 7;
  const int sw0  = ((q4)     ^ s8) * 8;   // kk=0 chunk
  const int sw1  = ((4 + q4) ^ s8) * 8;   // kk=1 chunk
  const int aRO  = (wr * 128 + fRow) * 64;

  auto dsA = [&](int buf, int mq) {
    const unsigned short* p = ldsA + buf * 16384 + aRO + mq * 4096;
#pragma unroll
    for (int m = 0; m < 4; ++m) {
      a[m][0] = *(const bf16x8*)(p + m * 1024 + sw0);
      a[m][1] = *(const bf16x8*)(p + m * 1024 + sw1);
    }
  };

  // ---- B direct loads: lane covers row nj*16+fRow of the wave's 64-col slab,
  // k-offset q4*8 within each 32-chunk. 4 dwordx4 per call, L2-resident.
  const unsigned short* gBr =
      B + (size_t)(bn * BN + wc * 64 + fRow) * K + q4 * 8;
  auto loadB = [&](int kt, int njp, bf16x8 (&bb)[2][2]) {
#pragma unroll
    for (int n = 0; n < 2; ++n)
#pragma unroll
      for (int kk = 0; kk < 2; ++kk)
        bb[n][kk] = *(const bf16x8*)(gBr + (size_t)((njp * 2 + n) * 16) * K +
                                     kt * BK + kk * 32);
  };

  auto mm32 = [&](int mq, bf16x8 (&b01)[2][2], bf16x8 (&b23)[2][2]) {
    __builtin_amdgcn_s_setprio(1);
#pragma unroll
    for (int m = 0; m < 4; ++m)
#pragma unroll
      for (int kk = 0; kk < 2; ++kk) {
        acc[mq * 4 + m][0] = __builtin_amdgcn_mfma_f32_16x16x32_bf16(
            a[m][kk], b01[0][kk], acc[mq * 4 + m][0], 0, 0, 0);
        acc[mq * 4 + m][1] = __builtin_amdgcn_mfma_f32_16x16x32_bf16(
            a[m][kk], b01[1][kk], acc[mq * 4 + m][1], 0, 0, 0);
        acc[mq * 4 + m][2] = __builtin_amdgcn_mfma_f32_16x16x32_bf16(
            a[m][kk], b23[0][kk], acc[mq * 4 + m][2], 0, 0, 0);
        acc[mq * 4 + m][3] = __builtin_amdgcn_mfma_f32_16x16x32_bf16(
            a[m][kk], b23[1][kk], acc[mq * 4 + m][3], 0, 0, 0);
      }
    __builtin_amdgcn_s_setprio(0);
  };

  // ---- prologue: tile 0 -> buf0; B(0) -> regs ----
  stageA(0, 0, 0); stageA(0, 1, 0); SB0();
  loadB(0, 0, b01e); loadB(0, 1, b23e); SB0();
  VMG(8);          // drain the 4 A stages (B's 8 remain; compiler waits those)
  BAR();

  const int ntile = K / BK;          // 16
  for (int i = 0; i < ntile / 2 - 1; ++i) {
    const int to = 2 * i + 1, te = 2 * i + 2;
    // E0: compute (buf0, mq0); stage A-U01(odd)->buf1; load b01(odd)
    dsA(0, 0); stageA(1, 0, to); SB0(); loadB(to, 0, b01o); SB0();
    BAR(); LG0(); mm32(0, b01e, b23e); VMG(10); BAR();
    // E1: (buf0, mq1); stage A-U23(odd); load b23(odd)
    dsA(0, 1); stageA(1, 1, to); SB0(); loadB(to, 1, b23o); SB0();
    BAR(); LG0(); mm32(1, b01e, b23e); VMG(10); BAR();
    // O0: (buf1, mq0); stage A-U01(next even)->buf0; load b01(next even)
    dsA(1, 0); stageA(0, 0, te); SB0(); loadB(te, 0, b01e); SB0();
    BAR(); LG0(); mm32(0, b01o, b23o); VMG(10); BAR();
    // O1: (buf1, mq1); stage A-U23(next even); load b23(next even)
    dsA(1, 1); stageA(0, 1, te); SB0(); loadB(te, 1, b23e); SB0();
    BAR(); LG0(); mm32(1, b01o, b23o); VMG(10); BAR();
  }
  // ---- peeled tiles ntile-2 (E, stages ntile-1) and ntile-1 (O, no issues) --
  {
    const int to = ntile - 1;
    dsA(0, 0); stageA(1, 0, to); SB0(); loadB(to, 0, b01o); SB0();
    BAR(); LG0(); mm32(0, b01e, b23e); VMG(10); BAR();
    dsA(0, 1); stageA(1, 1, to); SB0(); loadB(to, 1, b23o); SB0();
    BAR(); LG0(); mm32(1, b01e, b23e); VMG(10); BAR();
    // tile ntile-1: compiler's pre-mm wait for b23o (newest load) drains all
    // outstanding VMEM, including the A-U23 stage, before O1's ds reads.
    dsA(1, 0);
    BAR(); LG0(); mm32(0, b01o, b23o); VMG(0); BAR();
    dsA(1, 1);
    BAR(); LG0(); mm32(1, b01o, b23o);
  }

  // ---- epilogue: C/D map col=lane&15, row=(lane>>4)*4+reg ----
  const int    n0 = bn * BN + wc * 64 + fRow;
  const size_t m0 = (size_t)bm * BM + wr * 128 + (q4 << 2);
#pragma unroll
  for (int nj = 0; nj < 4; ++nj) {
    const int col = n0 + nj * 16;
    const float bv = bias[col];
#pragma unroll
    for (int mi = 0; mi < 8; ++mi) {
      const size_t base = (m0 + (size_t)mi * 16) * N + col;
#pragma unroll
      for (int r = 0; r < 4; ++r)
        C[base + (size_t)r * N] = acc[mi][nj][r] + bv;
    }
  }
}

// ---------- launch ----------
extern "C" void kernel_launch(void* const* d_in, const int* in_sizes, int n_in,
                              void* d_out, int out_size, void* d_ws, size_t ws_size,
                              hipStream_t stream) {
  const float* x    = (const float*)d_in[0];
  const float* w    = (const float*)d_in[1];
  const float* bias = (const float*)d_in[2];

  const int DOUT = in_sizes[2];            // 1024
  const int DIN  = in_sizes[1] / DOUT;     // 1024
  const int M    = in_sizes[0] / DIN;      // 32768

  unsigned short* xq = (unsigned short*)d_ws;                  // M*K bf16 = 64 MB
  unsigned short* wq = xq + (size_t)M * DIN;                   // N*K bf16 =  2 MB

  const int nw = (DOUT * DIN / 4) / 256;                       // 1024 blocks
  const int nx = (int)((size_t)M * DIN / 4 / 256);             // 32768 blocks
  hipLaunchKernelGGL(quant_xw, dim3(nw + nx), dim3(256), 0, stream,
                     x, xq, w, wq, nw);

  const int grid = (M / BM) * (DOUT / BN);  // 128*4 = 512
  hipLaunchKernelGGL(gemm_bt_bias, dim3(grid), dim3(512), 0, stream,
                     xq, wq, bias, (float*)d_out, M, DOUT, DIN);
}

// Round 4
// 315.965 us; speedup vs baseline: 1.1299x; 1.1299x over previous
//
#include <hip/hip_runtime.h>
#include <hip/hip_bf16.h>

// ---------- types ----------
typedef __bf16 bf16x8 __attribute__((ext_vector_type(8)));
typedef float  f32x4  __attribute__((ext_vector_type(4)));

#define GLOAD_LDS16(gptr, lptr)                                                  \
  __builtin_amdgcn_global_load_lds(                                              \
      (const __attribute__((address_space(1))) void*)(gptr),                     \
      (__attribute__((address_space(3))) void*)(lptr), 16, 0, 0)

__device__ __forceinline__ unsigned short f2bf(float f) {
  __hip_bfloat16 h = __float2bfloat16(f);
  return __builtin_bit_cast(unsigned short, h);
}

// ---------- fake-quant of one 128-elem block held by a 4-lane quad ----------
// Each lane owns 32 elements (any disjoint partition works: fmax commutative).
// Quad reduction = 2 x quad_perm DPP shuffles (VALU pipe, no LDS/ds_swizzle).
// Math identical to all prior rounds: amax=clip(max|x|,1e-12), scale=448/amax,
// q=RNE_fp8(clip(x*scale,+-448)) [HW cvt, OCP e4m3], deq=q*(amax/448).
__device__ __forceinline__ void fq32(float* __restrict__ v) {
  float am = 0.0f;
#pragma unroll
  for (int i = 0; i < 32; ++i) am = fmaxf(am, fabsf(v[i]));
  am = fmaxf(am, __shfl_xor(am, 1));   // quad_perm DPP
  am = fmaxf(am, __shfl_xor(am, 2));   // quad_perm DPP
  am = fmaxf(am, 1e-12f);
  const float scale = 448.0f / am;
  const float inv   = am * (1.0f / 448.0f);
#pragma unroll
  for (int i = 0; i < 32; i += 4) {
    float c0 = fminf(fmaxf(v[i + 0] * scale, -448.0f), 448.0f);
    float c1 = fminf(fmaxf(v[i + 1] * scale, -448.0f), 448.0f);
    float c2 = fminf(fmaxf(v[i + 2] * scale, -448.0f), 448.0f);
    float c3 = fminf(fmaxf(v[i + 3] * scale, -448.0f), 448.0f);
    int pk = __builtin_amdgcn_cvt_pk_fp8_f32(c0, c1, 0, false);
    pk = __builtin_amdgcn_cvt_pk_fp8_f32(c2, c3, pk, true);
    v[i + 0] = __builtin_amdgcn_cvt_f32_fp8(pk, 0) * inv;
    v[i + 1] = __builtin_amdgcn_cvt_f32_fp8(pk, 1) * inv;
    v[i + 2] = __builtin_amdgcn_cvt_f32_fp8(pk, 2) * inv;
    v[i + 3] = __builtin_amdgcn_cvt_f32_fp8(pk, 3) * inv;
  }
}

// Layout: wave covers 16 consecutive 128-blocks (2048 elems). Quad q owns
// block q; lane p(=lane&3) owns elems {i*16 + p*4 .. +3, i=0..7} of it.
// Load instr i: each quad reads a contiguous 64B sector; 16 quads at 512B
// stride tile 8KB densely -> 100% sector efficiency, zero L1 bounce.
__global__ __launch_bounds__(256) void quant_x_k(const float* __restrict__ x,
                                                 unsigned short* __restrict__ xq) {
  const size_t wave  = ((size_t)blockIdx.x * 256 + threadIdx.x) >> 6;
  const int    lane  = threadIdx.x & 63;
  const size_t qbase = wave * 2048 + (size_t)(lane >> 2) * 128 + (lane & 3) * 4;
  float v[32];
#pragma unroll
  for (int i = 0; i < 8; ++i)
    *(float4*)&v[i * 4] = *(const float4*)(x + qbase + i * 16);
  fq32(v);
#pragma unroll
  for (int i = 0; i < 8; ++i) {
    union { uint2 u; unsigned short s[4]; } pk;
#pragma unroll
    for (int e = 0; e < 4; ++e) pk.s[e] = f2bf(v[i * 4 + e]);
    *(uint2*)(xq + qbase + i * 16) = pk.u;
  }
}

// ---------- weight dual-quant: hi + fp8(residual), same layout ----------
__global__ __launch_bounds__(256) void quant_w_k(const float* __restrict__ w,
                                                 unsigned short* __restrict__ wq) {
  const size_t wave  = ((size_t)blockIdx.x * 256 + threadIdx.x) >> 6;
  const int    lane  = threadIdx.x & 63;
  const size_t qbase = wave * 2048 + (size_t)(lane >> 2) * 128 + (lane & 3) * 4;
  float a[32], h[32], r[32];
#pragma unroll
  for (int i = 0; i < 8; ++i)
    *(float4*)&a[i * 4] = *(const float4*)(w + qbase + i * 16);
#pragma unroll
  for (int i = 0; i < 32; ++i) h[i] = a[i];
  fq32(h);
#pragma unroll
  for (int i = 0; i < 32; ++i) r[i] = a[i] - h[i];
  fq32(r);
#pragma unroll
  for (int i = 0; i < 8; ++i) {
    union { uint2 u; unsigned short s[4]; } pk;
#pragma unroll
    for (int e = 0; e < 4; ++e) pk.s[e] = f2bf(h[i * 4 + e] + r[i * 4 + e]);
    *(uint2*)(wq + qbase + i * 16) = pk.u;
  }
}

// ---------- GEMM: 256x256 tile, BK=64, 8 waves (2Mx4N), 8-phase pipeline ----
// (exact round-2 kernel: measured 86 us, MfmaUtil 32%, 0 bank conflicts)
#define BM 256
#define BN 256
#define BK 64

#define VM4()  asm volatile("s_waitcnt vmcnt(4)" ::: "memory")
#define VM2()  asm volatile("s_waitcnt vmcnt(2)" ::: "memory")
#define VM0()  asm volatile("s_waitcnt vmcnt(0)" ::: "memory")
#define LG0()  do { asm volatile("s_waitcnt lgkmcnt(0)" ::: "memory");           \
                    __builtin_amdgcn_sched_barrier(0); } while (0)
#define BAR()  __builtin_amdgcn_s_barrier()

__global__ __launch_bounds__(512, 2) void gemm_bt_bias(
    const unsigned short* __restrict__ A,   // bf16 bits [M,K]
    const unsigned short* __restrict__ B,   // bf16 bits [N,K]
    const float* __restrict__ bias,         // [N]
    float* __restrict__ C,                  // [M,N]
    int M, int N, int K) {
  __shared__ unsigned short lds[65536];     // 128 KiB: A 2x16K elems, B 2x16K
  unsigned short* ldsA = lds;               // [buf][256][64]
  unsigned short* ldsB = lds + 32768;

  const int tid  = threadIdx.x;
  const int wv   = tid >> 6;
  const int lane = tid & 63;
  const int nbn  = N / BN;
  const int nbm  = M / BM;

  int bm, bn;
  if ((nbm & 7) == 0) {
    const int xcd = blockIdx.x & 7;
    const int j   = blockIdx.x >> 3;
    bn = j % nbn;
    bm = xcd * (nbm >> 3) + j / nbn;
  } else {
    bn = blockIdx.x % nbn;
    bm = blockIdx.x / nbn;
  }

  const int wr = wv >> 2;    // 0..1 (M dir, 128 rows each)
  const int wc = wv & 3;     // 0..3 (N dir, 64 cols each)

  f32x4  acc[8][4] = {};
  bf16x8 a[4][2], b01[2][2], b23[2][2];

  // ---- staging addresses (swizzle: LDS chunk c holds global chunk c^(row&7))
  const int    srcChunk = ((lane & 7) ^ ((lane >> 3) & 7)) * 8;
  const size_t laneSrc  = (size_t)(lane >> 3) * K + srcChunk;
  const unsigned short* gA = A + (size_t)bm * BM * K + laneSrc;
  const unsigned short* gB = B + (size_t)bn * BN * K + laneSrc;
  const int lr0 = wv * 16, lr1 = wv * 16 + 8;   // logical 8-row groups
  auto arow = [](int mq, int lr) { return mq * 64 + (lr < 64 ? lr : 64 + lr); };
  auto brow = [](int v,  int lr) { return v * 32 + (lr >> 5) * 64 + (lr & 31); };
  const int rA[2][2] = {{arow(0, lr0), arow(0, lr1)}, {arow(1, lr0), arow(1, lr1)}};
  const int rB[2][2] = {{brow(0, lr0), brow(0, lr1)}, {brow(1, lr0), brow(1, lr1)}};

  auto stageA = [&](int buf, int mq, int kt) {
#pragma unroll
    for (int t = 0; t < 2; ++t) {
      const int rb = rA[mq][t];
      GLOAD_LDS16(gA + (size_t)rb * K + kt * BK,
                  ldsA + buf * 16384 + rb * 64 + lane * 8);
    }
  };
  auto stageB = [&](int buf, int v, int kt) {
#pragma unroll
    for (int t = 0; t < 2; ++t) {
      const int rb = rB[v][t];
      GLOAD_LDS16(gB + (size_t)rb * K + kt * BK,
                  ldsB + buf * 16384 + rb * 64 + lane * 8);
    }
  };

  // ---- fragment reads (swizzled, 2-way free aliasing) --
  const int fRow = lane & 15;
  const int q4   = lane >> 4;
  const int s8   = fRow & 7;
  const int sw0  = ((q4)     ^ s8) * 8;   // kk=0 chunk
  const int sw1  = ((4 + q4) ^ s8) * 8;   // kk=1 chunk
  const int aRO  = (wr * 128 + fRow) * 64;
  const int bRO  = (wc * 64  + fRow) * 64;

  auto dsA = [&](int buf, int mq) {
    const unsigned short* p = ldsA + buf * 16384 + aRO + mq * 4096;
#pragma unroll
    for (int m = 0; m < 4; ++m) {
      a[m][0] = *(const bf16x8*)(p + m * 1024 + sw0);
      a[m][1] = *(const bf16x8*)(p + m * 1024 + sw1);
    }
  };
  auto dsB = [&](int buf, int njp, bf16x8 (&bb)[2][2]) {
    const unsigned short* p = ldsB + buf * 16384 + bRO + njp * 2048;
#pragma unroll
    for (int n = 0; n < 2; ++n) {
      bb[n][0] = *(const bf16x8*)(p + n * 1024 + sw0);
      bb[n][1] = *(const bf16x8*)(p + n * 1024 + sw1);
    }
  };

  auto mm = [&](int mq, int njp, bf16x8 (&bb)[2][2]) {
    __builtin_amdgcn_s_setprio(1);
#pragma unroll
    for (int m = 0; m < 4; ++m)
#pragma unroll
      for (int n = 0; n < 2; ++n)
#pragma unroll
        for (int k = 0; k < 2; ++k)
          acc[mq * 4 + m][njp * 2 + n] = __builtin_amdgcn_mfma_f32_16x16x32_bf16(
              a[m][k], bb[n][k], acc[mq * 4 + m][njp * 2 + n], 0, 0, 0);
    __builtin_amdgcn_s_setprio(0);
  };

  // ---- prologue: tile 0 -> buf0 (issue order matches steady-state gates) ---
  stageA(0, 0, 0); stageB(0, 0, 0); stageB(0, 1, 0); stageA(0, 1, 0);
  VM4(); BAR();

  const int niter = K / (2 * BK);   // 8 (K=1024); requires niter >= 2
  for (int i = 0; i < niter - 1; ++i) {
    const int t1 = 2 * i + 1, t2 = 2 * i + 2;
    // P0: compute buf0 (miQ0,nj01); stage buf1 A-U01
    dsA(0, 0); dsB(0, 0, b01); stageA(1, 0, t1);
    BAR(); LG0(); mm(0, 0, b01); VM4(); BAR();
    // P1: (miQ0,nj23); stage buf1 B-V0
    dsB(0, 1, b23); stageB(1, 0, t1);
    BAR(); LG0(); mm(0, 1, b23); VM4(); BAR();
    // P2: (miQ1,nj01); stage buf1 B-V1
    dsA(0, 1); stageB(1, 1, t1);
    BAR(); LG0(); mm(1, 0, b01); BAR();
    // P3: (miQ1,nj23); stage buf1 A-U23
    stageA(1, 1, t1);
    BAR(); mm(1, 1, b23); VM4(); BAR();
    // P4: compute buf1; stage buf0 A-U01 (next tile pair)
    dsA(1, 0); dsB(1, 0, b01); stageA(0, 0, t2);
    BAR(); LG0(); mm(0, 0, b01); VM4(); BAR();
    // P5
    dsB(1, 1, b23); stageB(0, 0, t2);
    BAR(); LG0(); mm(0, 1, b23); VM4(); BAR();
    // P6
    dsA(1, 1); stageB(0, 1, t2);
    BAR(); LG0(); mm(1, 0, b01); BAR();
    // P7
    stageA(0, 1, t2);
    BAR(); mm(1, 1, b23); VM4(); BAR();
  }
  // ---- peeled final iteration: no stages in P4-7; gates tighten 4->2->0 ----
  {
    const int t1 = 2 * niter - 1;
    dsA(0, 0); dsB(0, 0, b01); stageA(1, 0, t1);
    BAR(); LG0(); mm(0, 0, b01); VM4(); BAR();
    dsB(0, 1, b23); stageB(1, 0, t1);
    BAR(); LG0(); mm(0, 1, b23); VM4(); BAR();
    dsA(0, 1); stageB(1, 1, t1);
    BAR(); LG0(); mm(1, 0, b01); BAR();
    stageA(1, 1, t1);
    BAR(); mm(1, 1, b23); VM4(); BAR();
    dsA(1, 0); dsB(1, 0, b01);
    BAR(); LG0(); mm(0, 0, b01); VM2(); BAR();
    dsB(1, 1, b23);
    BAR(); LG0(); mm(0, 1, b23); VM0(); BAR();
    dsA(1, 1);
    BAR(); LG0(); mm(1, 0, b01); BAR();
    mm(1, 1, b23);
  }

  // ---- epilogue: C/D map col=lane&15, row=(lane>>4)*4+reg ----
  const int    n0 = bn * BN + wc * 64 + fRow;
  const size_t m0 = (size_t)bm * BM + wr * 128 + (q4 << 2);
#pragma unroll
  for (int nj = 0; nj < 4; ++nj) {
    const int col = n0 + nj * 16;
    const float bv = bias[col];
#pragma unroll
    for (int mi = 0; mi < 8; ++mi) {
      const size_t base = (m0 + (size_t)mi * 16) * N + col;
#pragma unroll
      for (int r = 0; r < 4; ++r)
        C[base + (size_t)r * N] = acc[mi][nj][r] + bv;
    }
  }
}

// ---------- launch ----------
extern "C" void kernel_launch(void* const* d_in, const int* in_sizes, int n_in,
                              void* d_out, int out_size, void* d_ws, size_t ws_size,
                              hipStream_t stream) {
  const float* x    = (const float*)d_in[0];
  const float* w    = (const float*)d_in[1];
  const float* bias = (const float*)d_in[2];

  const int DOUT = in_sizes[2];            // 1024
  const int DIN  = in_sizes[1] / DOUT;     // 1024
  const int M    = in_sizes[0] / DIN;      // 32768

  unsigned short* xq = (unsigned short*)d_ws;                  // M*K bf16 = 64 MB
  unsigned short* wq = xq + (size_t)M * DIN;                   // N*K bf16 =  2 MB

  // 32 elems per thread (quad-per-block layout)
  hipLaunchKernelGGL(quant_x_k, dim3((size_t)M * DIN / 32 / 256), dim3(256), 0,
                     stream, x, xq);
  hipLaunchKernelGGL(quant_w_k, dim3((size_t)DOUT * DIN / 32 / 256), dim3(256), 0,
                     stream, w, wq);

  const int grid = (M / BM) * (DOUT / BN);  // 128*4 = 512
  hipLaunchKernelGGL(gemm_bt_bias, dim3(grid), dim3(512), 0, stream,
                     xq, wq, bias, (float*)d_out, M, DOUT, DIN);
}

// Round 5
// 310.768 us; speedup vs baseline: 1.1488x; 1.0167x over previous
//
#include <hip/hip_runtime.h>
#include <hip/hip_bf16.h>

// ---------- types ----------
typedef __bf16 bf16x8 __attribute__((ext_vector_type(8)));
typedef float  f32x4  __attribute__((ext_vector_type(4)));

#define GLOAD_LDS16(gptr, lptr)                                                  \
  __builtin_amdgcn_global_load_lds(                                              \
      (const __attribute__((address_space(1))) void*)(gptr),                     \
      (__attribute__((address_space(3))) void*)(lptr), 16, 0, 0)

__device__ __forceinline__ unsigned short f2bf(float f) {
  __hip_bfloat16 h = __float2bfloat16(f);
  return __builtin_bit_cast(unsigned short, h);
}

// ---------- fake-quant of one 128-elem block held by a 4-lane quad ----------
// (unchanged from round 4)
__device__ __forceinline__ void fq32(float* __restrict__ v) {
  float am = 0.0f;
#pragma unroll
  for (int i = 0; i < 32; ++i) am = fmaxf(am, fabsf(v[i]));
  am = fmaxf(am, __shfl_xor(am, 1));   // quad_perm DPP
  am = fmaxf(am, __shfl_xor(am, 2));   // quad_perm DPP
  am = fmaxf(am, 1e-12f);
  const float scale = 448.0f / am;
  const float inv   = am * (1.0f / 448.0f);
#pragma unroll
  for (int i = 0; i < 32; i += 4) {
    float c0 = fminf(fmaxf(v[i + 0] * scale, -448.0f), 448.0f);
    float c1 = fminf(fmaxf(v[i + 1] * scale, -448.0f), 448.0f);
    float c2 = fminf(fmaxf(v[i + 2] * scale, -448.0f), 448.0f);
    float c3 = fminf(fmaxf(v[i + 3] * scale, -448.0f), 448.0f);
    int pk = __builtin_amdgcn_cvt_pk_fp8_f32(c0, c1, 0, false);
    pk = __builtin_amdgcn_cvt_pk_fp8_f32(c2, c3, pk, true);
    v[i + 0] = __builtin_amdgcn_cvt_f32_fp8(pk, 0) * inv;
    v[i + 1] = __builtin_amdgcn_cvt_f32_fp8(pk, 1) * inv;
    v[i + 2] = __builtin_amdgcn_cvt_f32_fp8(pk, 2) * inv;
    v[i + 3] = __builtin_amdgcn_cvt_f32_fp8(pk, 3) * inv;
  }
}

__global__ __launch_bounds__(256) void quant_x_k(const float* __restrict__ x,
                                                 unsigned short* __restrict__ xq) {
  const size_t wave  = ((size_t)blockIdx.x * 256 + threadIdx.x) >> 6;
  const int    lane  = threadIdx.x & 63;
  const size_t qbase = wave * 2048 + (size_t)(lane >> 2) * 128 + (lane & 3) * 4;
  float v[32];
#pragma unroll
  for (int i = 0; i < 8; ++i)
    *(float4*)&v[i * 4] = *(const float4*)(x + qbase + i * 16);
  fq32(v);
#pragma unroll
  for (int i = 0; i < 8; ++i) {
    union { uint2 u; unsigned short s[4]; } pk;
#pragma unroll
    for (int e = 0; e < 4; ++e) pk.s[e] = f2bf(v[i * 4 + e]);
    *(uint2*)(xq + qbase + i * 16) = pk.u;
  }
}

__global__ __launch_bounds__(256) void quant_w_k(const float* __restrict__ w,
                                                 unsigned short* __restrict__ wq) {
  const size_t wave  = ((size_t)blockIdx.x * 256 + threadIdx.x) >> 6;
  const int    lane  = threadIdx.x & 63;
  const size_t qbase = wave * 2048 + (size_t)(lane >> 2) * 128 + (lane & 3) * 4;
  float a[32], h[32], r[32];
#pragma unroll
  for (int i = 0; i < 8; ++i)
    *(float4*)&a[i * 4] = *(const float4*)(w + qbase + i * 16);
#pragma unroll
  for (int i = 0; i < 32; ++i) h[i] = a[i];
  fq32(h);
#pragma unroll
  for (int i = 0; i < 32; ++i) r[i] = a[i] - h[i];
  fq32(r);
#pragma unroll
  for (int i = 0; i < 8; ++i) {
    union { uint2 u; unsigned short s[4]; } pk;
#pragma unroll
    for (int e = 0; e < 4; ++e) pk.s[e] = f2bf(h[i * 4 + e] + r[i * 4 + e]);
    *(uint2*)(wq + qbase + i * 16) = pk.u;
  }
}

// ---------- GEMM: 256x128 tile, BK=64, 4 waves (2Mx2N), rolling SINGLE buffer
// LDS 48KB -> 2 blocks/CU: barrier drains in one block overlap compute in the
// other (the lever: r4 was 1 block/CU lockstep at 128KB). Units A-U01 (rows
// [0,64)+[128,192)), A-U23 (+64), B-V0 (rows r with (r&63)<32), B-V1 (rest).
// Phase p consumes its unit then the NEXT K-tile's copy is staged into the
// same region >=1 barrier later (WAR safe). Per-wave VMEM stream per K-tile:
// P1:U01'(4) P2:V0'(2) P3:V1'(2)+U23'(4) [SB0 pins V1' before U23'].
// Gates (FIFO-derived, never 0 in loop): P0-end vm(4)=>V1 landed;
// P1-end vm(4)=>U23 landed; P3-end vm(6)=>U01',V0' landed.
#define BM 256
#define BN 128
#define BK 64

#define VMG(n) asm volatile("s_waitcnt vmcnt(" #n ")" ::: "memory")
#define LG0()  do { asm volatile("s_waitcnt lgkmcnt(0)" ::: "memory");           \
                    __builtin_amdgcn_sched_barrier(0); } while (0)
#define SB0()  __builtin_amdgcn_sched_barrier(0)
#define BAR()  __builtin_amdgcn_s_barrier()

__global__ __launch_bounds__(256, 2) void gemm_bt_bias(
    const unsigned short* __restrict__ A,   // bf16 bits [M,K]
    const unsigned short* __restrict__ B,   // bf16 bits [N,K]
    const float* __restrict__ bias,         // [N]
    float* __restrict__ C,                  // [M,N]
    int M, int N, int K) {
  __shared__ unsigned short ldsA[BM * BK];  // 32 KB
  __shared__ unsigned short ldsB[BN * BK];  // 16 KB

  const int tid  = threadIdx.x;
  const int wv   = tid >> 6;     // 0..3
  const int lane = tid & 63;
  const int nbn  = N / BN;       // 8
  const int nbm  = M / BM;       // 128

  int bm, bn;
  if ((nbm & 7) == 0) {
    const int xcd = blockIdx.x & 7;
    const int j   = blockIdx.x >> 3;
    bn = j % nbn;                       // 8 consecutive same-XCD blocks share
    bm = xcd * (nbm >> 3) + j / nbn;    // one 512KB A-panel in that XCD's L2
  } else {
    bn = blockIdx.x % nbn;
    bm = blockIdx.x / nbn;
  }

  const int wr = wv >> 1;    // 0..1 (M dir, 128 rows each)
  const int wc = wv & 1;     // 0..1 (N dir, 64 cols each)

  f32x4  acc[8][4] = {};
  bf16x8 a[4][2], b01[2][2], b23[2][2];

  // ---- staging addresses (swizzle: LDS chunk c of row r holds global chunk
  // c^(r&7); src pre-swizzled since global_load_lds dst is linear)
  const int    srcChunk = ((lane & 7) ^ ((lane >> 3) & 7)) * 8;
  const size_t laneSrc  = (size_t)(lane >> 3) * K + srcChunk;
  const unsigned short* gA = A + (size_t)bm * BM * K + laneSrc;
  const unsigned short* gB = B + (size_t)bn * BN * K + laneSrc;

  // per-wave staged rows (all multiples of 8; +lane>>3 inside)
  int rU0[4], rV0[2];
#pragma unroll
  for (int t = 0; t < 4; ++t) {
    const int g = wv * 32 + t * 8;            // A-U01: [0,64)+[128,192)
    rU0[t] = (g < 64) ? g : g + 64;
  }
#pragma unroll
  for (int t = 0; t < 2; ++t) {
    const int g = wv * 16 + t * 8;            // B-V0: [0,32)+[64,96)
    rV0[t] = ((g >> 5) << 6) + (g & 31);
  }

  auto stageA = [&](int mq, int kt) {         // mq=0:U01, mq=1:U23 (+64)
#pragma unroll
    for (int t = 0; t < 4; ++t) {
      const int rb = rU0[t] + mq * 64;
      GLOAD_LDS16(gA + (size_t)rb * K + kt * BK, ldsA + rb * 64 + lane * 8);
    }
  };
  auto stageB = [&](int v, int kt) {          // v=0:V0, v=1:V1 (+32)
#pragma unroll
    for (int t = 0; t < 2; ++t) {
      const int rb = rV0[t] + v * 32;
      GLOAD_LDS16(gB + (size_t)rb * K + kt * BK, ldsB + rb * 64 + lane * 8);
    }
  };

  // ---- fragment reads (same proven swizzled pattern, 0 conflicts) ----
  const int fRow = lane & 15;
  const int q4   = lane >> 4;
  const int s8   = fRow & 7;
  const int sw0  = ((q4)     ^ s8) * 8;   // kk=0 chunk
  const int sw1  = ((4 + q4) ^ s8) * 8;   // kk=1 chunk
  const int aRO  = (wr * 128 + fRow) * 64;
  const int bRO  = (wc * 64  + fRow) * 64;

  auto dsA = [&](int mq) {
    const unsigned short* p = ldsA + aRO + mq * 4096;
#pragma unroll
    for (int m = 0; m < 4; ++m) {
      a[m][0] = *(const bf16x8*)(p + m * 1024 + sw0);
      a[m][1] = *(const bf16x8*)(p + m * 1024 + sw1);
    }
  };
  auto dsB = [&](int njp, bf16x8 (&bb)[2][2]) {
    const unsigned short* p = ldsB + bRO + njp * 2048;
#pragma unroll
    for (int n = 0; n < 2; ++n) {
      bb[n][0] = *(const bf16x8*)(p + n * 1024 + sw0);
      bb[n][1] = *(const bf16x8*)(p + n * 1024 + sw1);
    }
  };

  auto mm = [&](int mq, int njp, bf16x8 (&bb)[2][2]) {
    __builtin_amdgcn_s_setprio(1);
#pragma unroll
    for (int m = 0; m < 4; ++m)
#pragma unroll
      for (int n = 0; n < 2; ++n)
#pragma unroll
        for (int k = 0; k < 2; ++k)
          acc[mq * 4 + m][njp * 2 + n] = __builtin_amdgcn_mfma_f32_16x16x32_bf16(
              a[m][k], bb[n][k], acc[mq * 4 + m][njp * 2 + n], 0, 0, 0);
    __builtin_amdgcn_s_setprio(0);
  };

  // ---- prologue: tile 0, issue order U01,V0,V1,U23 (matches steady gates) --
  stageA(0, 0); SB0(); stageB(0, 0); SB0(); stageB(1, 0); SB0(); stageA(1, 0);
  VMG(6); BAR();

  const int ntile = K / BK;          // 16
  for (int t = 0; t < ntile - 1; ++t) {
    // P0: consume U01,V0; no stage (regions not yet free)
    dsA(0); dsB(0, b01);
    BAR(); LG0(); mm(0, 0, b01); VMG(4); BAR();
    // P1: consume V1; stage U01(t+1) over U01 (read done at P0-end barrier)
    dsB(1, b23); stageA(0, t + 1);
    BAR(); LG0(); mm(0, 1, b23); VMG(4); BAR();
    // P2: consume U23; stage V0(t+1)
    dsA(1); stageB(0, t + 1);
    BAR(); LG0(); mm(1, 0, b01); BAR();
    // P3: stage V1(t+1) then U23(t+1)  [SB0 pins V1' older than U23']
    stageB(1, t + 1); SB0(); stageA(1, t + 1);
    BAR(); mm(1, 1, b23); VMG(6); BAR();
  }
  // ---- peeled last K-tile: no stages; gates tighten 4 -> 0 ----
  {
    dsA(0); dsB(0, b01);
    BAR(); LG0(); mm(0, 0, b01); VMG(4); BAR();
    dsB(1, b23);
    BAR(); LG0(); mm(0, 1, b23); VMG(0); BAR();
    dsA(1);
    BAR(); LG0(); mm(1, 0, b01); BAR();
    mm(1, 1, b23);
  }

  // ---- epilogue: C/D map col=lane&15, row=(lane>>4)*4+reg ----
  const int    n0 = bn * BN + wc * 64 + fRow;
  const size_t m0 = (size_t)bm * BM + wr * 128 + (q4 << 2);
#pragma unroll
  for (int nj = 0; nj < 4; ++nj) {
    const int col = n0 + nj * 16;
    const float bv = bias[col];
#pragma unroll
    for (int mi = 0; mi < 8; ++mi) {
      const size_t base = (m0 + (size_t)mi * 16) * N + col;
#pragma unroll
      for (int r = 0; r < 4; ++r)
        C[base + (size_t)r * N] = acc[mi][nj][r] + bv;
    }
  }
}

// ---------- launch ----------
extern "C" void kernel_launch(void* const* d_in, const int* in_sizes, int n_in,
                              void* d_out, int out_size, void* d_ws, size_t ws_size,
                              hipStream_t stream) {
  const float* x    = (const float*)d_in[0];
  const float* w    = (const float*)d_in[1];
  const float* bias = (const float*)d_in[2];

  const int DOUT = in_sizes[2];            // 1024
  const int DIN  = in_sizes[1] / DOUT;     // 1024
  const int M    = in_sizes[0] / DIN;      // 32768

  unsigned short* xq = (unsigned short*)d_ws;                  // M*K bf16 = 64 MB
  unsigned short* wq = xq + (size_t)M * DIN;                   // N*K bf16 =  2 MB

  hipLaunchKernelGGL(quant_x_k, dim3((size_t)M * DIN / 32 / 256), dim3(256), 0,
                     stream, x, xq);
  hipLaunchKernelGGL(quant_w_k, dim3((size_t)DOUT * DIN / 32 / 256), dim3(256), 0,
                     stream, w, wq);

  const int grid = (M / BM) * (DOUT / BN);  // 128*8 = 1024
  hipLaunchKernelGGL(gemm_bt_bias, dim3(grid), dim3(256), 0, stream,
                     xq, wq, bias, (float*)d_out, M, DOUT, DIN);
}

// Round 7
// 310.601 us; speedup vs baseline: 1.1494x; 1.0005x over previous
//
#include <hip/hip_runtime.h>
#include <hip/hip_bf16.h>

// ---------- types ----------
typedef __bf16 bf16x8 __attribute__((ext_vector_type(8)));
typedef float  f32x4  __attribute__((ext_vector_type(4)));

#define GLOAD_LDS16(gptr, lptr)                                                  \
  __builtin_amdgcn_global_load_lds(                                              \
      (const __attribute__((address_space(1))) void*)(gptr),                     \
      (__attribute__((address_space(3))) void*)(lptr), 16, 0, 0)

__device__ __forceinline__ unsigned short f2bf(float f) {
  __hip_bfloat16 h = __float2bfloat16(f);
  return __builtin_bit_cast(unsigned short, h);
}

// ---------- fake-quant of one 128-elem block held by a 4-lane quad ----------
// (unchanged from round 5)
__device__ __forceinline__ void fq32(float* __restrict__ v) {
  float am = 0.0f;
#pragma unroll
  for (int i = 0; i < 32; ++i) am = fmaxf(am, fabsf(v[i]));
  am = fmaxf(am, __shfl_xor(am, 1));   // quad_perm DPP
  am = fmaxf(am, __shfl_xor(am, 2));   // quad_perm DPP
  am = fmaxf(am, 1e-12f);
  const float scale = 448.0f / am;
  const float inv   = am * (1.0f / 448.0f);
#pragma unroll
  for (int i = 0; i < 32; i += 4) {
    float c0 = fminf(fmaxf(v[i + 0] * scale, -448.0f), 448.0f);
    float c1 = fminf(fmaxf(v[i + 1] * scale, -448.0f), 448.0f);
    float c2 = fminf(fmaxf(v[i + 2] * scale, -448.0f), 448.0f);
    float c3 = fminf(fmaxf(v[i + 3] * scale, -448.0f), 448.0f);
    int pk = __builtin_amdgcn_cvt_pk_fp8_f32(c0, c1, 0, false);
    pk = __builtin_amdgcn_cvt_pk_fp8_f32(c2, c3, pk, true);
    v[i + 0] = __builtin_amdgcn_cvt_f32_fp8(pk, 0) * inv;
    v[i + 1] = __builtin_amdgcn_cvt_f32_fp8(pk, 1) * inv;
    v[i + 2] = __builtin_amdgcn_cvt_f32_fp8(pk, 2) * inv;
    v[i + 3] = __builtin_amdgcn_cvt_f32_fp8(pk, 3) * inv;
  }
}

__global__ __launch_bounds__(256) void quant_x_k(const float* __restrict__ x,
                                                 unsigned short* __restrict__ xq) {
  const size_t wave  = ((size_t)blockIdx.x * 256 + threadIdx.x) >> 6;
  const int    lane  = threadIdx.x & 63;
  const size_t qbase = wave * 2048 + (size_t)(lane >> 2) * 128 + (lane & 3) * 4;
  float v[32];
#pragma unroll
  for (int i = 0; i < 8; ++i)
    *(float4*)&v[i * 4] = *(const float4*)(x + qbase + i * 16);
  fq32(v);
#pragma unroll
  for (int i = 0; i < 8; ++i) {
    union { uint2 u; unsigned short s[4]; } pk;
#pragma unroll
    for (int e = 0; e < 4; ++e) pk.s[e] = f2bf(v[i * 4 + e]);
    *(uint2*)(xq + qbase + i * 16) = pk.u;
  }
}

__global__ __launch_bounds__(256) void quant_w_k(const float* __restrict__ w,
                                                 unsigned short* __restrict__ wq) {
  const size_t wave  = ((size_t)blockIdx.x * 256 + threadIdx.x) >> 6;
  const int    lane  = threadIdx.x & 63;
  const size_t qbase = wave * 2048 + (size_t)(lane >> 2) * 128 + (lane & 3) * 4;
  float a[32], h[32], r[32];
#pragma unroll
  for (int i = 0; i < 8; ++i)
    *(float4*)&a[i * 4] = *(const float4*)(w + qbase + i * 16);
#pragma unroll
  for (int i = 0; i < 32; ++i) h[i] = a[i];
  fq32(h);
#pragma unroll
  for (int i = 0; i < 32; ++i) r[i] = a[i] - h[i];
  fq32(r);
#pragma unroll
  for (int i = 0; i < 8; ++i) {
    union { uint2 u; unsigned short s[4]; } pk;
#pragma unroll
    for (int e = 0; e < 4; ++e) pk.s[e] = f2bf(h[i * 4 + e] + r[i * 4 + e]);
    *(uint2*)(wq + qbase + i * 16) = pk.u;
  }
}

// ---------- GEMM: 256x128 tile, BK=64, 4 waves (2Mx2N), rolling SINGLE buffer
// 48KB LDS -> 2 blocks/CU. One barrier per phase in the MAIN loop; every
// phase-boundary read-gate keeps the order: own-VMG drain -> BAR -> reads
// (cross-wave RAW safe: vmcnt is per-wave, so the drain must precede the
// barrier that releases readers). WAR safe: every ds read is consumed by its
// own phase's mm before the wave reaches the end-of-phase barrier; stages of
// a region issue only after that barrier.
// PEEL KEEPS ITS TWO GATE BARRIERS (r6 lesson: removing them races — the
// VMG(4)/VMG(0) drains only the executing wave's loads; other waves' V1'/U23'
// need drain->BAR before being read).
// Per-wave VMEM stream per K-tile: P1:U01'(4) P2:V0'(2) P3:V1'(2)+U23'(4).
// Gates: P0-end vm(4)=>V1 landed; P1-end vm(4)=>U23 landed;
// P3-end vm(6)=>U01',V0' landed. Never 0 in the main loop.
#define BM 256
#define BN 128
#define BK 64

#define VMG(n) asm volatile("s_waitcnt vmcnt(" #n ")" ::: "memory")
#define SB0()  __builtin_amdgcn_sched_barrier(0)
#define BAR()  __builtin_amdgcn_s_barrier()

__global__ __launch_bounds__(256, 2) void gemm_bt_bias(
    const unsigned short* __restrict__ A,   // bf16 bits [M,K]
    const unsigned short* __restrict__ B,   // bf16 bits [N,K]
    const float* __restrict__ bias,         // [N]
    float* __restrict__ C,                  // [M,N]
    int M, int N, int K) {
  __shared__ unsigned short ldsA[BM * BK];  // 32 KB
  __shared__ unsigned short ldsB[BN * BK];  // 16 KB

  const int tid  = threadIdx.x;
  const int wv   = tid >> 6;     // 0..3
  const int lane = tid & 63;
  const int nbn  = N / BN;       // 8
  const int nbm  = M / BM;       // 128

  int bm, bn;
  if ((nbm & 7) == 0) {
    const int xcd = blockIdx.x & 7;
    const int j   = blockIdx.x >> 3;
    bn = j % nbn;                       // 8 consecutive same-XCD blocks share
    bm = xcd * (nbm >> 3) + j / nbn;    // one A-panel in that XCD's L2
  } else {
    bn = blockIdx.x % nbn;
    bm = blockIdx.x / nbn;
  }

  const int wr = wv >> 1;    // 0..1 (M dir, 128 rows each)
  const int wc = wv & 1;     // 0..1 (N dir, 64 cols each)

  f32x4  acc[8][4] = {};
  bf16x8 a[4][2], b01[2][2], b23[2][2];

  // ---- staging addresses (swizzle: LDS chunk c of row r holds global chunk
  // c^(r&7); src pre-swizzled since global_load_lds dst is linear)
  const int    srcChunk = ((lane & 7) ^ ((lane >> 3) & 7)) * 8;
  const size_t laneSrc  = (size_t)(lane >> 3) * K + srcChunk;
  const unsigned short* gA = A + (size_t)bm * BM * K + laneSrc;
  const unsigned short* gB = B + (size_t)bn * BN * K + laneSrc;

  // per-wave staged rows (all multiples of 8; +lane>>3 inside)
  int rU0[4], rV0[2];
#pragma unroll
  for (int t = 0; t < 4; ++t) {
    const int g = wv * 32 + t * 8;            // A-U01: [0,64)+[128,192)
    rU0[t] = (g < 64) ? g : g + 64;
  }
#pragma unroll
  for (int t = 0; t < 2; ++t) {
    const int g = wv * 16 + t * 8;            // B-V0: [0,32)+[64,96)
    rV0[t] = ((g >> 5) << 6) + (g & 31);
  }

  auto stageA = [&](int mq, int kt) {         // mq=0:U01, mq=1:U23 (+64)
#pragma unroll
    for (int t = 0; t < 4; ++t) {
      const int rb = rU0[t] + mq * 64;
      GLOAD_LDS16(gA + (size_t)rb * K + kt * BK, ldsA + rb * 64 + lane * 8);
    }
  };
  auto stageB = [&](int v, int kt) {          // v=0:V0, v=1:V1 (+32)
#pragma unroll
    for (int t = 0; t < 2; ++t) {
      const int rb = rV0[t] + v * 32;
      GLOAD_LDS16(gB + (size_t)rb * K + kt * BK, ldsB + rb * 64 + lane * 8);
    }
  };

  // ---- fragment reads (same proven swizzled pattern, 0 conflicts) ----
  const int fRow = lane & 15;
  const int q4   = lane >> 4;
  const int s8   = fRow & 7;
  const int sw0  = ((q4)     ^ s8) * 8;   // kk=0 chunk
  const int sw1  = ((4 + q4) ^ s8) * 8;   // kk=1 chunk
  const int aRO  = (wr * 128 + fRow) * 64;
  const int bRO  = (wc * 64  + fRow) * 64;

  auto dsA = [&](int mq) {
    const unsigned short* p = ldsA + aRO + mq * 4096;
#pragma unroll
    for (int m = 0; m < 4; ++m) {
      a[m][0] = *(const bf16x8*)(p + m * 1024 + sw0);
      a[m][1] = *(const bf16x8*)(p + m * 1024 + sw1);
    }
  };
  auto dsB = [&](int njp, bf16x8 (&bb)[2][2]) {
    const unsigned short* p = ldsB + bRO + njp * 2048;
#pragma unroll
    for (int n = 0; n < 2; ++n) {
      bb[n][0] = *(const bf16x8*)(p + n * 1024 + sw0);
      bb[n][1] = *(const bf16x8*)(p + n * 1024 + sw1);
    }
  };

  auto mm = [&](int mq, int njp, bf16x8 (&bb)[2][2]) {
    __builtin_amdgcn_s_setprio(1);
#pragma unroll
    for (int m = 0; m < 4; ++m)
#pragma unroll
      for (int n = 0; n < 2; ++n)
#pragma unroll
        for (int k = 0; k < 2; ++k)
          acc[mq * 4 + m][njp * 2 + n] = __builtin_amdgcn_mfma_f32_16x16x32_bf16(
              a[m][k], bb[n][k], acc[mq * 4 + m][njp * 2 + n], 0, 0, 0);
    __builtin_amdgcn_s_setprio(0);
  };

  // ---- prologue: tile 0, issue order U01,V0,V1,U23 (matches steady gates) --
  stageA(0, 0); SB0(); stageB(0, 0); SB0(); stageB(1, 0); SB0(); stageA(1, 0);
  VMG(6); BAR(); SB0();

  const int ntile = K / BK;          // 16
  for (int t = 0; t < ntile - 1; ++t) {
    // P0: consume U01,V0 (no stage; regions not yet free)
    dsA(0); dsB(0, b01);
    mm(0, 0, b01);
    VMG(4); BAR(); SB0();            // V1 landed (drain BEFORE barrier)
    // P1: stage U01(t+1) first; consume V1
    stageA(0, t + 1); SB0();
    dsB(1, b23);
    mm(0, 1, b23);
    VMG(4); BAR(); SB0();            // U23 landed
    // P2: stage V0(t+1); consume U23
    stageB(0, t + 1); SB0();
    dsA(1);
    mm(1, 0, b01);
    BAR(); SB0();                    // (P3 reads nothing new: no gate)
    // P3: stage V1(t+1) then U23(t+1); compute from regs
    stageB(1, t + 1); SB0(); stageA(1, t + 1); SB0();
    mm(1, 1, b23);
    VMG(6); BAR(); SB0();            // U01',V0' landed
  }
  // ---- peeled last K-tile: no stages; KEEP the two gate barriers ----------
  {
    dsA(0); dsB(0, b01);
    mm(0, 0, b01);
    VMG(4); BAR(); SB0();            // all waves' V1' drained before V1 read
    dsB(1, b23);
    mm(0, 1, b23);
    VMG(0); BAR(); SB0();            // all waves' U23' drained before U23 read
    dsA(1);
    mm(1, 0, b01);
    mm(1, 1, b23);
  }

  // ---- epilogue: C/D map col=lane&15, row=(lane>>4)*4+reg ----
  const int    n0 = bn * BN + wc * 64 + fRow;
  const size_t m0 = (size_t)bm * BM + wr * 128 + (q4 << 2);
#pragma unroll
  for (int nj = 0; nj < 4; ++nj) {
    const int col = n0 + nj * 16;
    const float bv = bias[col];
#pragma unroll
    for (int mi = 0; mi < 8; ++mi) {
      const size_t base = (m0 + (size_t)mi * 16) * N + col;
#pragma unroll
      for (int r = 0; r < 4; ++r)
        C[base + (size_t)r * N] = acc[mi][nj][r] + bv;
    }
  }
}

// ---------- launch ----------
extern "C" void kernel_launch(void* const* d_in, const int* in_sizes, int n_in,
                              void* d_out, int out_size, void* d_ws, size_t ws_size,
                              hipStream_t stream) {
  const float* x    = (const float*)d_in[0];
  const float* w    = (const float*)d_in[1];
  const float* bias = (const float*)d_in[2];

  const int DOUT = in_sizes[2];            // 1024
  const int DIN  = in_sizes[1] / DOUT;     // 1024
  const int M    = in_sizes[0] / DIN;      // 32768

  unsigned short* xq = (unsigned short*)d_ws;                  // M*K bf16 = 64 MB
  unsigned short* wq = xq + (size_t)M * DIN;                   // N*K bf16 =  2 MB

  hipLaunchKernelGGL(quant_x_k, dim3((size_t)M * DIN / 32 / 256), dim3(256), 0,
                     stream, x, xq);
  hipLaunchKernelGGL(quant_w_k, dim3((size_t)DOUT * DIN / 32 / 256), dim3(256), 0,
                     stream, w, wq);

  const int grid = (M / BM) * (DOUT / BN);  // 128*8 = 1024
  hipLaunchKernelGGL(gemm_bt_bias, dim3(grid), dim3(256), 0, stream,
                     xq, wq, bias, (float*)d_out, M, DOUT, DIN);
}